// Round 1
// 319.338 us; speedup vs baseline: 1.0126x; 1.0126x over previous
//
#include <hip/hip_runtime.h>

// Native clang vector: __builtin_nontemporal_* requires a real vector type,
// not HIP's struct-based float4.
typedef float vf4 __attribute__((ext_vector_type(4)));

// SPU(v) = v^2 - 0.5        for v >= 0
//        = sigmoid(-v) - 1  for v <  0  ( = -e^v/(1+e^v) )
// Branchless: compute both, select. For huge +v, the neg path gives NaN
// (inf * rcp(inf)) but is discarded by the select. For v -> -inf, neg -> -0. OK.
// v_rcp_f32 approx (~1e-7 rel) is fine: absmax threshold is 1.08, measured 0.03.
__device__ __forceinline__ float spu_f(float v) {
    float e   = __expf(v);                                    // v_exp_f32
    float neg = -e * __builtin_amdgcn_rcpf(1.f + e);          // v_rcp_f32, no IEEE divide
    float pos = fmaf(v, v, -0.5f);
    return v >= 0.f ? pos : neg;                              // v_cndmask
}

__device__ __forceinline__ void compute4(vf4 xv, vf4 lv, vf4 uv,
                                         vf4& xr, vf4& lr, vf4& ur) {
#pragma unroll
    for (int k = 0; k < 4; ++k) {
        float xk = xv[k], lk = lv[k], uk = uv[k];

        float sl  = spu_f(lk);
        float su  = spu_f(uk);
        float ssu = spu_f(su);   // only used when l<0 && u<=0 (su in [-0.5,0) there)

        // l_out = l>=0 ? spu(l) : (u<=0 ? spu(u) : -0.5)
        lr[k] = lk >= 0.f ? sl : (uk <= 0.f ? su : -0.5f);
        // u_out = (l<0 && u<=0) ? spu(spu(u)) : spu(u)
        ur[k] = (lk < 0.f && uk <= 0.f) ? ssu : su;
        xr[k] = spu_f(xk);
    }
}

#define CHUNKS 4   // float4s per thread; 4096 blocks cover n4 = 4194304 exactly

__global__ __launch_bounds__(256) void spu_layer_kernel(
    const vf4* __restrict__ x,
    const vf4* __restrict__ l,
    const vf4* __restrict__ u,
    vf4* __restrict__ xo,
    vf4* __restrict__ lo,
    vf4* __restrict__ uo,
    int n4)
{
    int base = blockIdx.x * (256 * CHUNKS) + threadIdx.x;

    if (base + 256 * (CHUNKS - 1) < n4) {
        // Fast path (always taken at DIM=16M): issue ALL 12 loads before any
        // dependent compute -> 12 wave-level 1KiB transactions in flight,
        // consumed in order at vmcnt(9)/vmcnt(6)/vmcnt(3)/vmcnt(0).
        vf4 xv[CHUNKS], lv[CHUNKS], uv[CHUNKS];
#pragma unroll
        for (int c = 0; c < CHUNKS; ++c) {
            int i = base + c * 256;
            xv[c] = __builtin_nontemporal_load(x + i);
            lv[c] = __builtin_nontemporal_load(l + i);
            uv[c] = __builtin_nontemporal_load(u + i);
        }
#pragma unroll
        for (int c = 0; c < CHUNKS; ++c) {
            int i = base + c * 256;
            vf4 xr, lr, ur;
            compute4(xv[c], lv[c], uv[c], xr, lr, ur);
            __builtin_nontemporal_store(xr, xo + i);
            __builtin_nontemporal_store(lr, lo + i);
            __builtin_nontemporal_store(ur, uo + i);
        }
    } else {
        // Tail path (never taken when n4 % 1024 == 0) — per-chunk guard.
        for (int c = 0; c < CHUNKS; ++c) {
            int i = base + c * 256;
            if (i < n4) {
                vf4 xv = __builtin_nontemporal_load(x + i);
                vf4 lv = __builtin_nontemporal_load(l + i);
                vf4 uv = __builtin_nontemporal_load(u + i);
                vf4 xr, lr, ur;
                compute4(xv, lv, uv, xr, lr, ur);
                __builtin_nontemporal_store(xr, xo + i);
                __builtin_nontemporal_store(lr, lo + i);
                __builtin_nontemporal_store(ur, uo + i);
            }
        }
    }
}

extern "C" void kernel_launch(void* const* d_in, const int* in_sizes, int n_in,
                              void* d_out, int out_size, void* d_ws, size_t ws_size,
                              hipStream_t stream) {
    const float* x = (const float*)d_in[0];
    const float* l = (const float*)d_in[1];
    const float* u = (const float*)d_in[2];
    float* out = (float*)d_out;

    const int n  = in_sizes[0];          // 16777216
    const int n4 = n / 4;                // 4194304 float4s per stream

    float* xo = out;
    float* lo = out + n;
    float* uo = out + 2 * (size_t)n;

    dim3 block(256);
    dim3 grid((n4 + (256 * CHUNKS - 1)) / (256 * CHUNKS));   // 4096 blocks
    spu_layer_kernel<<<grid, block, 0, stream>>>(
        (const vf4*)x, (const vf4*)l, (const vf4*)u,
        (vf4*)xo, (vf4*)lo, (vf4*)uo, n4);
}